// Round 2
// baseline (405.351 us; speedup 1.0000x reference)
//
#include <hip/hip_runtime.h>

// ---------------------------------------------------------------------------
// MultiHeadAttention: B=8, T=1024, E=256(head dim), H=8, TEMP=16
// Pipeline: x->bf16 | W->bf16,transposed | QKV gemms | flash attn | FC gemm
// All matmuls: v_mfma_f32_16x16x32_bf16, fp32 accumulate.
// Mask input is int32 (0/1), True==masked.
// ---------------------------------------------------------------------------

typedef __attribute__((ext_vector_type(8))) short bf16x8;
typedef __attribute__((ext_vector_type(4))) float f32x4;
typedef __attribute__((ext_vector_type(4))) unsigned short u16x4;
typedef __attribute__((ext_vector_type(2))) unsigned int u32x2;
typedef __attribute__((ext_vector_type(4))) int i32x4;

#define B_DIM 8
#define T_DIM 1024
#define E_DIM 256
#define H_DIM 8

__device__ __forceinline__ unsigned short f2bf(float f) {
  unsigned u = __builtin_bit_cast(unsigned, f);
  u += 0x7FFFu + ((u >> 16) & 1u);   // RNE, finite values only
  return (unsigned short)(u >> 16);
}

__device__ __forceinline__ void gload_lds16(const void* g, void* l) {
  __builtin_amdgcn_global_load_lds(
      (const __attribute__((address_space(1))) void*)g,
      (__attribute__((address_space(3))) void*)l, 16, 0, 0);
}

__device__ __forceinline__ f32x4 mfma16(bf16x8 a, bf16x8 b, f32x4 c) {
  return __builtin_amdgcn_mfma_f32_16x16x32_bf16(a, b, c, 0, 0, 0);
}

// --------------------------- x -> bf16 cast --------------------------------
__global__ __launch_bounds__(256) void xcast_kernel(const float* __restrict__ in,
                                                    unsigned short* __restrict__ out,
                                                    int n4) {
  int i = blockIdx.x * 256 + threadIdx.x;
  if (i >= n4) return;
  f32x4 v = ((const f32x4*)in)[i];
  u16x4 o = { f2bf(v[0]), f2bf(v[1]), f2bf(v[2]), f2bf(v[3]) };
  ((u16x4*)out)[i] = o;
}

// ----------------- weight transpose + bf16: in[K][N] -> out[N][K] ----------
__global__ __launch_bounds__(256) void wtrans_kernel(const float* __restrict__ in,
                                                     unsigned short* __restrict__ out,
                                                     int K, int N) {
  __shared__ unsigned short tile[64][65];
  int n0 = blockIdx.x * 64, k0 = blockIdx.y * 64;
  int tid = threadIdx.x;
#pragma unroll
  for (int p = 0; p < 16; ++p) {
    int i = p * 256 + tid;
    int r = i >> 6, c = i & 63;
    tile[c][r] = f2bf(in[(size_t)(k0 + r) * N + n0 + c]);
  }
  __syncthreads();
#pragma unroll
  for (int p = 0; p < 16; ++p) {
    int i = p * 256 + tid;
    int r = i >> 6, c = i & 63;
    out[(size_t)(n0 + r) * K + k0 + c] = tile[r][c];
  }
}

// --------------------------- GEMM (bf16 in, modes) -------------------------
// C[M,N] = A[M,K] * BT[N,K]^T.  128x128 tile, BK=64, 256 thr, 4 waves (2x2).
// MODE 0: f32 out + bias (FC).  MODE 1: bf16 out at [b][h][t][e].
// MODE 2: bf16 out at [b][h][e][t] (transposed, for V).
template <int MODE>
__global__ __launch_bounds__(256) void gemm_kernel(
    const unsigned short* __restrict__ A, const unsigned short* __restrict__ BT,
    const float* __restrict__ bias, void* __restrict__ Cout,
    int M, int N, int K, float scale) {
  __shared__ unsigned short As[128 * 64];
  __shared__ unsigned short Bs[128 * 64];
  const int tid = threadIdx.x;
  const int w = tid >> 6, l = tid & 63, lg = l >> 4, lr = l & 15;
  const int tn = blockIdx.x * 128, tm = blockIdx.y * 128;
  const int wm = (w >> 1) * 64, wn = (w & 1) * 64;

  f32x4 acc[4][4];
#pragma unroll
  for (int i = 0; i < 4; ++i)
#pragma unroll
    for (int j = 0; j < 4; ++j) acc[i][j] = (f32x4){0.f, 0.f, 0.f, 0.f};

  for (int kt = 0; kt < K; kt += 64) {
    // stage A tile [128][64] bf16, XOR-swizzled via pre-swizzled source
#pragma unroll
    for (int j = 0; j < 4; ++j) {
      int d = j * 4096 + w * 1024 + l * 16;
      int row = d >> 7, cb = d & 127;
      gload_lds16((const char*)(A + (size_t)(tm + row) * K + kt) + (cb ^ ((row & 7) << 4)),
                  (char*)As + j * 4096 + w * 1024);
    }
#pragma unroll
    for (int j = 0; j < 4; ++j) {
      int d = j * 4096 + w * 1024 + l * 16;
      int row = d >> 7, cb = d & 127;
      gload_lds16((const char*)(BT + (size_t)(tn + row) * K + kt) + (cb ^ ((row & 7) << 4)),
                  (char*)Bs + j * 4096 + w * 1024);
    }
    __syncthreads();
#pragma unroll
    for (int c = 0; c < 2; ++c) {
      bf16x8 af[4], bfr[4];
#pragma unroll
      for (int mf = 0; mf < 4; ++mf) {
        int row = wm + mf * 16 + lr;
        af[mf] = *(const bf16x8*)((const char*)As + row * 128 +
                                  ((c * 64 + lg * 16) ^ ((row & 7) << 4)));
      }
#pragma unroll
      for (int nf = 0; nf < 4; ++nf) {
        int row = wn + nf * 16 + lr;
        bfr[nf] = *(const bf16x8*)((const char*)Bs + row * 128 +
                                   ((c * 64 + lg * 16) ^ ((row & 7) << 4)));
      }
#pragma unroll
      for (int mf = 0; mf < 4; ++mf)
#pragma unroll
        for (int nf = 0; nf < 4; ++nf)
          acc[mf][nf] = mfma16(af[mf], bfr[nf], acc[mf][nf]);
    }
    __syncthreads();
  }

#pragma unroll
  for (int mf = 0; mf < 4; ++mf) {
#pragma unroll
    for (int nf = 0; nf < 4; ++nf) {
      int col = tn + wn + nf * 16 + lr;
      int row0 = tm + wm + mf * 16 + lg * 4;
      if constexpr (MODE == 0) {
        float bv = bias[col];
        float* C = (float*)Cout;
#pragma unroll
        for (int r = 0; r < 4; ++r)
          C[(size_t)(row0 + r) * N + col] = acc[mf][nf][r] * scale + bv;
      } else if constexpr (MODE == 1) {
        unsigned short* C = (unsigned short*)Cout;
#pragma unroll
        for (int r = 0; r < 4; ++r) {
          int rowm = row0 + r;
          int bi = rowm >> 10, t = rowm & 1023, hh = col >> 8, e = col & 255;
          C[(((size_t)bi * H_DIM + hh) * T_DIM + t) * E_DIM + e] =
              f2bf(acc[mf][nf][r] * scale);
        }
      } else {
        unsigned short* C = (unsigned short*)Cout;
        int bi = row0 >> 10, t0 = row0 & 1023, hh = col >> 8, e = col & 255;
        u16x4 pk = { f2bf(acc[mf][nf][0] * scale), f2bf(acc[mf][nf][1] * scale),
                     f2bf(acc[mf][nf][2] * scale), f2bf(acc[mf][nf][3] * scale) };
        *(u16x4*)&C[(((size_t)bi * H_DIM + hh) * E_DIM + e) * T_DIM + t0] = pk;
      }
    }
  }
}

// ------------------------------ flash attention ----------------------------
// Grid (16 q-tiles, 64 b*h). 4 waves; wave w owns q rows w*16..w*16+15.
// qb,kb: [bh][t][e] bf16 (q pre-scaled by 1/16). vtb: [bh][e][t] bf16.
// Swapped QK^T: S^T[kv][q] so lane (l&15)=q owns one q-row's scores.
// mask: int32 [b][t][t], nonzero == masked.
__global__ __launch_bounds__(256) void attn_kernel(
    const unsigned short* __restrict__ qb, const unsigned short* __restrict__ kb,
    const unsigned short* __restrict__ vtb, const int* __restrict__ mask,
    unsigned short* __restrict__ aout) {
  __shared__ unsigned short Kt[64 * 256];   // [kv][e], swizzled
  __shared__ unsigned short Vt[256 * 64];   // [e][kv], swizzled
  __shared__ unsigned short Pt[4][16 * 64]; // per-wave P [q][kv], swizzled

  const int tid = threadIdx.x;
  const int w = tid >> 6, l = tid & 63, lg = l >> 4, lr = l & 15;
  const int qt = blockIdx.x, bh = blockIdx.y;
  const int b = bh >> 3, h = bh & 7;

  const unsigned short* qg = qb + (size_t)bh * T_DIM * E_DIM + (size_t)(qt * 64) * E_DIM;
  const unsigned short* kg = kb + (size_t)bh * T_DIM * E_DIM;
  // per-lane mask row pointer: q row = qt*64 + w*16 + lr
  const int* mrow = mask + (size_t)b * T_DIM * T_DIM +
                    (size_t)(qt * 64 + w * 16 + lr) * T_DIM;
  const char* vgc = (const char*)(vtb + (size_t)bh * E_DIM * T_DIM);

  // Q fragments: row = w*16+lr, k = c*32 + lg*8
  bf16x8 qf[8];
  {
    const unsigned short* qrow = qg + (size_t)(w * 16 + lr) * E_DIM + lg * 8;
#pragma unroll
    for (int c = 0; c < 8; ++c) qf[c] = *(const bf16x8*)(qrow + c * 32);
  }

  f32x4 O[16];
#pragma unroll
  for (int i = 0; i < 16; ++i) O[i] = (f32x4){0.f, 0.f, 0.f, 0.f};
  float m_run = -INFINITY, l_run = 0.f;

  for (int kt = 0; kt < 16; ++kt) {
    // ---- stage K tile (64x256, contiguous 32KB), pre-swizzled source
    const char* ksrc = (const char*)(kg + (size_t)(kt * 64) * E_DIM);
#pragma unroll
    for (int j = 0; j < 8; ++j) {
      int d = j * 4096 + w * 1024 + l * 16;
      int row = d >> 9, cb = d & 511;
      gload_lds16(ksrc + row * 512 + (cb ^ ((row & 7) << 4)),
                  (char*)Kt + j * 4096 + w * 1024);
    }
    // ---- stage V^T tile (256 rows x 64 kv)
#pragma unroll
    for (int j = 0; j < 8; ++j) {
      int d = j * 4096 + w * 1024 + l * 16;
      int row = d >> 7, cb = d & 127;
      gload_lds16(vgc + (size_t)row * 2048 + kt * 128 + (cb ^ ((row & 7) << 4)),
                  (char*)Vt + j * 4096 + w * 1024);
    }
    // ---- per-lane mask regs: kv = kvf*16 + lg*4 + r
    i32x4 mv[4];
#pragma unroll
    for (int kvf = 0; kvf < 4; ++kvf)
      mv[kvf] = *(const i32x4*)(mrow + kt * 64 + kvf * 16 + lg * 4);
    __syncthreads();

    // ---- S^T = K * Q^T : D[kv][q], col(l&15)=q, row(lg*4+r)=kv
    f32x4 S[4];
#pragma unroll
    for (int i = 0; i < 4; ++i) S[i] = (f32x4){0.f, 0.f, 0.f, 0.f};
#pragma unroll
    for (int kvf = 0; kvf < 4; ++kvf) {
      int row = kvf * 16 + lr;
      const char* abase = (const char*)Kt + row * 512;
      int swz = (row & 7) << 4;
#pragma unroll
      for (int c = 0; c < 8; ++c) {
        bf16x8 a = *(const bf16x8*)(abase + ((c * 64 + lg * 16) ^ swz));
        S[kvf] = mfma16(a, qf[c], S[kvf]);
      }
    }

    // ---- mask + online softmax (lane owns q = w*16+lr; kv = kvf*16+lg*4+r)
    float p[4][4];
    float tmax = -INFINITY;
#pragma unroll
    for (int kvf = 0; kvf < 4; ++kvf) {
#pragma unroll
      for (int r = 0; r < 4; ++r) {
        float sv = S[kvf][r];
        if (mv[kvf][r] != 0) sv = -INFINITY;
        p[kvf][r] = sv;
        tmax = fmaxf(tmax, sv);
      }
    }
    tmax = fmaxf(tmax, __shfl_xor(tmax, 16, 64));
    tmax = fmaxf(tmax, __shfl_xor(tmax, 32, 64));
    float m_new = fmaxf(m_run, tmax);
    float msafe = fmaxf(m_new, -1e30f);       // finite guard: all-masked rows
    float alpha = __expf(m_run - msafe);      // -inf -> 0 (l,O are 0 then)
    float rsum = 0.f;
#pragma unroll
    for (int kvf = 0; kvf < 4; ++kvf)
#pragma unroll
      for (int r = 0; r < 4; ++r) {
        float e = __expf(p[kvf][r] - msafe);  // -inf -> 0
        p[kvf][r] = e;
        rsum += e;
      }
    rsum += __shfl_xor(rsum, 16, 64);
    rsum += __shfl_xor(rsum, 32, 64);
    l_run = l_run * alpha + rsum;
    m_run = m_new;

    // ---- write P (bf16) to per-wave LDS, swizzled; 4 consecutive kv per write
    {
      char* pb = (char*)(Pt[w]) + lr * 128;
      int swz = (lr & 7) << 4;
#pragma unroll
      for (int kvf = 0; kvf < 4; ++kvf) {
        u32x2 pk;
        pk[0] = (unsigned)f2bf(p[kvf][0]) | ((unsigned)f2bf(p[kvf][1]) << 16);
        pk[1] = (unsigned)f2bf(p[kvf][2]) | ((unsigned)f2bf(p[kvf][3]) << 16);
        *(u32x2*)(pb + ((kvf * 32 + lg * 8) ^ swz)) = pk;
      }
    }

    // ---- rescale O rows (row m = lg*4+r) by alpha of that q-row
    {
      float av0 = __shfl(alpha, lg * 4 + 0, 64);
      float av1 = __shfl(alpha, lg * 4 + 1, 64);
      float av2 = __shfl(alpha, lg * 4 + 2, 64);
      float av3 = __shfl(alpha, lg * 4 + 3, 64);
#pragma unroll
      for (int nf = 0; nf < 16; ++nf) {
        O[nf][0] *= av0; O[nf][1] *= av1; O[nf][2] *= av2; O[nf][3] *= av3;
      }
    }

    // ---- PV: O[q][e] += P[q][kv] * V[kv][e]
#pragma unroll
    for (int c2 = 0; c2 < 2; ++c2) {
      const char* pbase = (const char*)(Pt[w]) + lr * 128;
      bf16x8 pa = *(const bf16x8*)(pbase + ((c2 * 64 + lg * 16) ^ ((lr & 7) << 4)));
#pragma unroll
      for (int nf = 0; nf < 16; ++nf) {
        int vrow = nf * 16 + lr;
        bf16x8 vb = *(const bf16x8*)((const char*)Vt + vrow * 128 +
                                     ((c2 * 64 + lg * 16) ^ ((vrow & 7) << 4)));
        O[nf] = mfma16(pa, vb, O[nf]);
      }
    }
    __syncthreads();
  }

  // ---- epilogue: O/l (0 if fully masked), store bf16 [b][t][h*256+e]
  float lv[4];
#pragma unroll
  for (int r = 0; r < 4; ++r) {
    float lval = __shfl(l_run, lg * 4 + r, 64);
    lv[r] = lval > 0.f ? 1.f / lval : 0.f;
  }
  const int qrow0 = qt * 64 + w * 16 + lg * 4;
  unsigned short* obase = aout + (size_t)(b * T_DIM) * 2048 + h * 256;
#pragma unroll
  for (int nf = 0; nf < 16; ++nf) {
#pragma unroll
    for (int r = 0; r < 4; ++r) {
      obase[(size_t)(qrow0 + r) * 2048 + nf * 16 + lr] = f2bf(O[nf][r] * lv[r]);
    }
  }
}

// ------------------------------- launcher ----------------------------------
extern "C" void kernel_launch(void* const* d_in, const int* in_sizes, int n_in,
                              void* d_out, int out_size, void* d_ws, size_t ws_size,
                              hipStream_t stream) {
  (void)in_sizes; (void)n_in; (void)out_size; (void)ws_size;
  const float* x    = (const float*)d_in[0];
  const float* Wq   = (const float*)d_in[1];
  const float* Wk   = (const float*)d_in[2];
  const float* Wv   = (const float*)d_in[3];
  const float* Wfc  = (const float*)d_in[4];
  const float* bfc  = (const float*)d_in[5];
  const int* mask   = (const int*)d_in[6];
  float* out = (float*)d_out;

  char* ws = (char*)d_ws;
  unsigned short* xbf  = (unsigned short*)(ws + 0);          //  4 MB [8192][256]
  unsigned short* qbuf = (unsigned short*)(ws + 4194304);    // 32 MB [bh][t][e]
  unsigned short* kbuf = (unsigned short*)(ws + 37748736);   // 32 MB [bh][t][e]
  unsigned short* vbuf = (unsigned short*)(ws + 71303168);   // 32 MB [bh][e][t]
  unsigned short* abuf = (unsigned short*)(ws + 104857600);  // 32 MB [8192][2048]
  unsigned short* wqT  = (unsigned short*)(ws + 138412032);  //  1 MB [2048][256]
  unsigned short* wkT  = (unsigned short*)(ws + 139460608);
  unsigned short* wvT  = (unsigned short*)(ws + 140509184);
  unsigned short* wfcT = (unsigned short*)(ws + 141557760);  //  1 MB [256][2048]

  xcast_kernel<<<2048, 256, 0, stream>>>(x, xbf, 524288);
  wtrans_kernel<<<dim3(32, 4), 256, 0, stream>>>(Wq, wqT, 256, 2048);
  wtrans_kernel<<<dim3(32, 4), 256, 0, stream>>>(Wk, wkT, 256, 2048);
  wtrans_kernel<<<dim3(32, 4), 256, 0, stream>>>(Wv, wvT, 256, 2048);
  wtrans_kernel<<<dim3(4, 32), 256, 0, stream>>>(Wfc, wfcT, 2048, 256);

  // Q gets the 1/TEMP = 1/16 scale baked in before bf16 store.
  gemm_kernel<1><<<dim3(16, 64), 256, 0, stream>>>(xbf, wqT, nullptr, qbuf,
                                                   8192, 2048, 256, 1.0f / 16.0f);
  gemm_kernel<1><<<dim3(16, 64), 256, 0, stream>>>(xbf, wkT, nullptr, kbuf,
                                                   8192, 2048, 256, 1.0f);
  gemm_kernel<2><<<dim3(16, 64), 256, 0, stream>>>(xbf, wvT, nullptr, vbuf,
                                                   8192, 2048, 256, 1.0f);

  attn_kernel<<<dim3(16, 64), 256, 0, stream>>>(qbuf, kbuf, vbuf, mask, abuf);

  gemm_kernel<0><<<dim3(2, 64), 256, 0, stream>>>(abuf, wfcT, bfc, out,
                                                  8192, 256, 2048, 1.0f);
}

// Round 4
// 314.661 us; speedup vs baseline: 1.2882x; 1.2882x over previous
//
#include <hip/hip_runtime.h>

// ---------------------------------------------------------------------------
// MultiHeadAttention: B=8, T=1024, E=256(head dim), H=8, TEMP=16
// Pipeline: x->bf16 | W->bf16,transposed | mask bit-pack | QKV gemms |
//           flash attn (8-wave, dbuf K/V, stage-early) | FC gemm
// All matmuls: v_mfma_f32_16x16x32_bf16, fp32 accumulate.
// Mask input is int32 (0/1), nonzero == masked; packed to 1 bit/elem.
// ---------------------------------------------------------------------------

typedef __attribute__((ext_vector_type(8))) short bf16x8;
typedef __attribute__((ext_vector_type(4))) float f32x4;
typedef __attribute__((ext_vector_type(4))) unsigned short u16x4;
typedef __attribute__((ext_vector_type(2))) unsigned int u32x2;
typedef __attribute__((ext_vector_type(4))) int i32x4;

#define B_DIM 8
#define T_DIM 1024
#define E_DIM 256
#define H_DIM 8

__device__ __forceinline__ unsigned short f2bf(float f) {
  unsigned u = __builtin_bit_cast(unsigned, f);
  u += 0x7FFFu + ((u >> 16) & 1u);   // RNE, finite values only
  return (unsigned short)(u >> 16);
}

__device__ __forceinline__ void gload_lds16(const void* g, void* l) {
  __builtin_amdgcn_global_load_lds(
      (const __attribute__((address_space(1))) void*)g,
      (__attribute__((address_space(3))) void*)l, 16, 0, 0);
}

__device__ __forceinline__ f32x4 mfma16(bf16x8 a, bf16x8 b, f32x4 c) {
  return __builtin_amdgcn_mfma_f32_16x16x32_bf16(a, b, c, 0, 0, 0);
}

// --------------------------- x -> bf16 cast --------------------------------
__global__ __launch_bounds__(256) void xcast_kernel(const float* __restrict__ in,
                                                    unsigned short* __restrict__ out,
                                                    int n4) {
  int i = blockIdx.x * 256 + threadIdx.x;
  if (i >= n4) return;
  f32x4 v = ((const f32x4*)in)[i];
  u16x4 o = { f2bf(v[0]), f2bf(v[1]), f2bf(v[2]), f2bf(v[3]) };
  ((u16x4*)out)[i] = o;
}

// -------------------- mask int32 -> 1 bit per element ----------------------
__global__ __launch_bounds__(256) void mpack_kernel(const int* __restrict__ m,
                                                    unsigned char* __restrict__ out,
                                                    int n8) {
  int i = blockIdx.x * 256 + threadIdx.x;   // one output byte per thread
  if (i >= n8) return;
  i32x4 a = ((const i32x4*)m)[i * 2];
  i32x4 b = ((const i32x4*)m)[i * 2 + 1];
  unsigned v = 0;
  v |= (a[0] != 0) ? 1u : 0u;
  v |= (a[1] != 0) ? 2u : 0u;
  v |= (a[2] != 0) ? 4u : 0u;
  v |= (a[3] != 0) ? 8u : 0u;
  v |= (b[0] != 0) ? 16u : 0u;
  v |= (b[1] != 0) ? 32u : 0u;
  v |= (b[2] != 0) ? 64u : 0u;
  v |= (b[3] != 0) ? 128u : 0u;
  out[i] = (unsigned char)v;
}

// ----------------- weight transpose + bf16: in[K][N] -> out[N][K] ----------
__global__ __launch_bounds__(256) void wtrans_kernel(const float* __restrict__ in,
                                                     unsigned short* __restrict__ out,
                                                     int K, int N) {
  __shared__ unsigned short tile[64][65];
  int n0 = blockIdx.x * 64, k0 = blockIdx.y * 64;
  int tid = threadIdx.x;
#pragma unroll
  for (int p = 0; p < 16; ++p) {
    int i = p * 256 + tid;
    int r = i >> 6, c = i & 63;
    tile[c][r] = f2bf(in[(size_t)(k0 + r) * N + n0 + c]);
  }
  __syncthreads();
#pragma unroll
  for (int p = 0; p < 16; ++p) {
    int i = p * 256 + tid;
    int r = i >> 6, c = i & 63;
    out[(size_t)(n0 + r) * K + k0 + c] = tile[r][c];
  }
}

// --------------------------- GEMM (bf16 in, modes) -------------------------
// C[M,N] = A[M,K] * BT[N,K]^T.  128x128 tile, BK=64, 256 thr, 4 waves (2x2).
// MODE 0: f32 out + bias (FC).  MODE 1: bf16 out at [b][h][t][e].
// MODE 2: bf16 out at [b][h][e][t] (transposed, for V).
template <int MODE>
__global__ __launch_bounds__(256) void gemm_kernel(
    const unsigned short* __restrict__ A, const unsigned short* __restrict__ BT,
    const float* __restrict__ bias, void* __restrict__ Cout,
    int M, int N, int K, float scale) {
  __shared__ unsigned short As[128 * 64];
  __shared__ unsigned short Bs[128 * 64];
  const int tid = threadIdx.x;
  const int w = tid >> 6, l = tid & 63, lg = l >> 4, lr = l & 15;
  const int tn = blockIdx.x * 128, tm = blockIdx.y * 128;
  const int wm = (w >> 1) * 64, wn = (w & 1) * 64;

  f32x4 acc[4][4];
#pragma unroll
  for (int i = 0; i < 4; ++i)
#pragma unroll
    for (int j = 0; j < 4; ++j) acc[i][j] = (f32x4){0.f, 0.f, 0.f, 0.f};

  for (int kt = 0; kt < K; kt += 64) {
    // stage A tile [128][64] bf16, XOR-swizzled via pre-swizzled source
#pragma unroll
    for (int j = 0; j < 4; ++j) {
      int d = j * 4096 + w * 1024 + l * 16;
      int row = d >> 7, cb = d & 127;
      gload_lds16((const char*)(A + (size_t)(tm + row) * K + kt) + (cb ^ ((row & 7) << 4)),
                  (char*)As + j * 4096 + w * 1024);
    }
#pragma unroll
    for (int j = 0; j < 4; ++j) {
      int d = j * 4096 + w * 1024 + l * 16;
      int row = d >> 7, cb = d & 127;
      gload_lds16((const char*)(BT + (size_t)(tn + row) * K + kt) + (cb ^ ((row & 7) << 4)),
                  (char*)Bs + j * 4096 + w * 1024);
    }
    __syncthreads();
#pragma unroll
    for (int c = 0; c < 2; ++c) {
      bf16x8 af[4], bfr[4];
#pragma unroll
      for (int mf = 0; mf < 4; ++mf) {
        int row = wm + mf * 16 + lr;
        af[mf] = *(const bf16x8*)((const char*)As + row * 128 +
                                  ((c * 64 + lg * 16) ^ ((row & 7) << 4)));
      }
#pragma unroll
      for (int nf = 0; nf < 4; ++nf) {
        int row = wn + nf * 16 + lr;
        bfr[nf] = *(const bf16x8*)((const char*)Bs + row * 128 +
                                   ((c * 64 + lg * 16) ^ ((row & 7) << 4)));
      }
#pragma unroll
      for (int mf = 0; mf < 4; ++mf)
#pragma unroll
        for (int nf = 0; nf < 4; ++nf)
          acc[mf][nf] = mfma16(af[mf], bfr[nf], acc[mf][nf]);
    }
    __syncthreads();
  }

#pragma unroll
  for (int mf = 0; mf < 4; ++mf) {
#pragma unroll
    for (int nf = 0; nf < 4; ++nf) {
      int col = tn + wn + nf * 16 + lr;
      int row0 = tm + wm + mf * 16 + lg * 4;
      if constexpr (MODE == 0) {
        float bv = bias[col];
        float* C = (float*)Cout;
#pragma unroll
        for (int r = 0; r < 4; ++r)
          C[(size_t)(row0 + r) * N + col] = acc[mf][nf][r] * scale + bv;
      } else if constexpr (MODE == 1) {
        unsigned short* C = (unsigned short*)Cout;
#pragma unroll
        for (int r = 0; r < 4; ++r) {
          int rowm = row0 + r;
          int bi = rowm >> 10, t = rowm & 1023, hh = col >> 8, e = col & 255;
          C[(((size_t)bi * H_DIM + hh) * T_DIM + t) * E_DIM + e] =
              f2bf(acc[mf][nf][r] * scale);
        }
      } else {
        unsigned short* C = (unsigned short*)Cout;
        int bi = row0 >> 10, t0 = row0 & 1023, hh = col >> 8, e = col & 255;
        u16x4 pk = { f2bf(acc[mf][nf][0] * scale), f2bf(acc[mf][nf][1] * scale),
                     f2bf(acc[mf][nf][2] * scale), f2bf(acc[mf][nf][3] * scale) };
        *(u16x4*)&C[(((size_t)bi * H_DIM + hh) * E_DIM + e) * T_DIM + t0] = pk;
      }
    }
  }
}

// ------------------------------ flash attention ----------------------------
// 512 blocks x 512 thr (8 waves). Block = (bh, qt): 128 q rows, wave w owns
// rows w*16..w*16+15.  K/V double-buffered in LDS (stage-early: issue tile
// t+1 loads before computing tile t; single __syncthreads per tile — the
// barrier's vmcnt drain lands after ~4K cycles of compute, so no stall).
// qb,kb: [bh][t][e] bf16 (q pre-scaled by 1/16). vtb: [bh][e][t] bf16.
// mpk: bit-packed mask, u64 = 64 kv positions per (b, qrow) per tile.
// Swapped QK^T: S^T[kv][q] so lane (l&15)=q owns one q-row's scores.
__global__ __launch_bounds__(512) void attn_kernel(
    const unsigned short* __restrict__ qb, const unsigned short* __restrict__ kb,
    const unsigned short* __restrict__ vtb,
    const unsigned long long* __restrict__ mpk,
    unsigned short* __restrict__ aout) {
  __shared__ unsigned short Kt[2][64 * 256];   // [kv][e], swizzled   (2x32KB)
  __shared__ unsigned short Vt[2][256 * 64];   // [e][kv], swizzled   (2x32KB)
  __shared__ unsigned short Pt[8][16 * 64];    // per-wave P [q][kv]  (16KB)

  const int tid = threadIdx.x;
  const int w = tid >> 6, l = tid & 63, lg = l >> 4, lr = l & 15;
  // XCD-aware swizzle: XCD x owns bh 8x..8x+7; q-tiles of one bh consecutive.
  const int bid = blockIdx.x;
  const int x = bid & 7, j = bid >> 3;
  const int bh = x * 8 + (j >> 3), qt = j & 7;
  const int b = bh >> 3, h = bh & 7;

  const unsigned short* qg = qb + (size_t)bh * T_DIM * E_DIM + (size_t)(qt * 128) * E_DIM;
  const unsigned short* kg = kb + (size_t)bh * T_DIM * E_DIM;
  const char* vgc = (const char*)(vtb + (size_t)bh * E_DIM * T_DIM);
  // packed mask row for this lane's q row (16 u64 per row)
  const unsigned long long* mrow =
      mpk + ((size_t)b * T_DIM + qt * 128 + w * 16 + lr) * 16;

  // stage K/V tile kt into buffer bufi (all 8 waves cooperate)
  auto stageKV = [&](int bufi, int kt) {
    const char* ksrc = (const char*)(kg + (size_t)(kt * 64) * E_DIM);
    char* kdst = (char*)Kt[bufi];
    char* vdst = (char*)Vt[bufi];
#pragma unroll
    for (int j2 = 0; j2 < 4; ++j2) {
      int d = j2 * 8192 + w * 1024 + l * 16;
      int row = d >> 9, cb = d & 511;
      gload_lds16(ksrc + row * 512 + (cb ^ ((row & 7) << 4)), kdst + d);
    }
#pragma unroll
    for (int j2 = 0; j2 < 4; ++j2) {
      int d = j2 * 8192 + w * 1024 + l * 16;
      int row = d >> 7, cb = d & 127;
      gload_lds16(vgc + (size_t)row * 2048 + kt * 128 + (cb ^ ((row & 7) << 4)),
                  vdst + d);
    }
  };

  // prologue: stage tile 0; load Q fragments meanwhile
  stageKV(0, 0);
  bf16x8 qf[8];
  {
    const unsigned short* qrow = qg + (size_t)(w * 16 + lr) * E_DIM + lg * 8;
#pragma unroll
    for (int c = 0; c < 8; ++c) qf[c] = *(const bf16x8*)(qrow + c * 32);
  }

  f32x4 O[16];
#pragma unroll
  for (int i = 0; i < 16; ++i) O[i] = (f32x4){0.f, 0.f, 0.f, 0.f};
  float m_run = -INFINITY, l_run = 0.f;

  __syncthreads();

  for (int kt = 0; kt < 16; ++kt) {
    const int cur = kt & 1;
    // mask bits for this tile (issued before stage so its wait leaves the
    // stage loads in flight)
    unsigned long long m64 = mrow[kt];
    // stage next tile into the other buffer while we compute this one
    if (kt < 15) stageKV(cur ^ 1, kt + 1);

    // ---- S^T = K * Q^T : D[kv][q], col(l&15)=q, row(lg*4+r)=kv
    f32x4 S[4];
#pragma unroll
    for (int i = 0; i < 4; ++i) S[i] = (f32x4){0.f, 0.f, 0.f, 0.f};
    __builtin_amdgcn_s_setprio(1);
#pragma unroll
    for (int kvf = 0; kvf < 4; ++kvf) {
      int row = kvf * 16 + lr;
      const char* abase = (const char*)Kt[cur] + row * 512;
      int swz = (row & 7) << 4;
#pragma unroll
      for (int c = 0; c < 8; ++c) {
        bf16x8 a = *(const bf16x8*)(abase + ((c * 64 + lg * 16) ^ swz));
        S[kvf] = mfma16(a, qf[c], S[kvf]);
      }
    }
    __builtin_amdgcn_s_setprio(0);

    // ---- mask + online softmax (lane owns q = w*16+lr; kv = kvf*16+lg*4+r)
    float p[4][4];
    float tmax = -INFINITY;
#pragma unroll
    for (int kvf = 0; kvf < 4; ++kvf) {
      unsigned nib = (unsigned)(m64 >> (kvf * 16 + lg * 4)) & 0xFu;
#pragma unroll
      for (int r = 0; r < 4; ++r) {
        float sv = S[kvf][r];
        if (nib & (1u << r)) sv = -INFINITY;
        p[kvf][r] = sv;
        tmax = fmaxf(tmax, sv);
      }
    }
    tmax = fmaxf(tmax, __shfl_xor(tmax, 16, 64));
    tmax = fmaxf(tmax, __shfl_xor(tmax, 32, 64));
    float m_new = fmaxf(m_run, tmax);
    float msafe = fmaxf(m_new, -1e30f);       // finite guard: all-masked rows
    float alpha = __expf(m_run - msafe);      // -inf -> 0 (l,O are 0 then)
    float rsum = 0.f;
#pragma unroll
    for (int kvf = 0; kvf < 4; ++kvf)
#pragma unroll
      for (int r = 0; r < 4; ++r) {
        float e = __expf(p[kvf][r] - msafe);  // -inf -> 0
        p[kvf][r] = e;
        rsum += e;
      }
    rsum += __shfl_xor(rsum, 16, 64);
    rsum += __shfl_xor(rsum, 32, 64);
    l_run = l_run * alpha + rsum;
    m_run = m_new;

    // ---- write P (bf16) to per-wave LDS, swizzled
    {
      char* pb = (char*)(Pt[w]) + lr * 128;
      int swz = (lr & 7) << 4;
#pragma unroll
      for (int kvf = 0; kvf < 4; ++kvf) {
        u32x2 pk;
        pk[0] = (unsigned)f2bf(p[kvf][0]) | ((unsigned)f2bf(p[kvf][1]) << 16);
        pk[1] = (unsigned)f2bf(p[kvf][2]) | ((unsigned)f2bf(p[kvf][3]) << 16);
        *(u32x2*)(pb + ((kvf * 32 + lg * 8) ^ swz)) = pk;
      }
    }

    // ---- rescale O rows (row m = lg*4+r) by alpha of that q-row
    {
      float av0 = __shfl(alpha, lg * 4 + 0, 64);
      float av1 = __shfl(alpha, lg * 4 + 1, 64);
      float av2 = __shfl(alpha, lg * 4 + 2, 64);
      float av3 = __shfl(alpha, lg * 4 + 3, 64);
#pragma unroll
      for (int nf = 0; nf < 16; ++nf) {
        O[nf][0] *= av0; O[nf][1] *= av1; O[nf][2] *= av2; O[nf][3] *= av3;
      }
    }

    // ---- PV: O[q][e] += P[q][kv] * V[kv][e]
    __builtin_amdgcn_s_setprio(1);
#pragma unroll
    for (int c2 = 0; c2 < 2; ++c2) {
      const char* pbase = (const char*)(Pt[w]) + lr * 128;
      bf16x8 pa = *(const bf16x8*)(pbase + ((c2 * 64 + lg * 16) ^ ((lr & 7) << 4)));
#pragma unroll
      for (int nf = 0; nf < 16; ++nf) {
        int vrow = nf * 16 + lr;
        bf16x8 vb = *(const bf16x8*)((const char*)Vt[cur] + vrow * 128 +
                                     ((c2 * 64 + lg * 16) ^ ((vrow & 7) << 4)));
        O[nf] = mfma16(pa, vb, O[nf]);
      }
    }
    __builtin_amdgcn_s_setprio(0);

    // single barrier per tile: drains stage loads (issued ~4K cycles ago,
    // already landed) and ensures all waves are done reading buf[cur]
    // before it becomes the stage target next iteration.
    __syncthreads();
  }

  // ---- epilogue: O/l (0 if fully masked), store bf16 [b][t][h*256+e]
  float lv[4];
#pragma unroll
  for (int r = 0; r < 4; ++r) {
    float lval = __shfl(l_run, lg * 4 + r, 64);
    lv[r] = lval > 0.f ? 1.f / lval : 0.f;
  }
  const int qrow0 = qt * 128 + w * 16 + lg * 4;
  unsigned short* obase = aout + (size_t)(b * T_DIM) * 2048 + h * 256;
#pragma unroll
  for (int nf = 0; nf < 16; ++nf) {
#pragma unroll
    for (int r = 0; r < 4; ++r) {
      obase[(size_t)(qrow0 + r) * 2048 + nf * 16 + lr] = f2bf(O[nf][r] * lv[r]);
    }
  }
}

// ------------------------------- launcher ----------------------------------
extern "C" void kernel_launch(void* const* d_in, const int* in_sizes, int n_in,
                              void* d_out, int out_size, void* d_ws, size_t ws_size,
                              hipStream_t stream) {
  (void)in_sizes; (void)n_in; (void)out_size; (void)ws_size;
  const float* x    = (const float*)d_in[0];
  const float* Wq   = (const float*)d_in[1];
  const float* Wk   = (const float*)d_in[2];
  const float* Wv   = (const float*)d_in[3];
  const float* Wfc  = (const float*)d_in[4];
  const float* bfc  = (const float*)d_in[5];
  const int* mask   = (const int*)d_in[6];
  float* out = (float*)d_out;

  char* ws = (char*)d_ws;
  unsigned short* xbf  = (unsigned short*)(ws + 0);          //  4 MB [8192][256]
  unsigned short* qbuf = (unsigned short*)(ws + 4194304);    // 32 MB [bh][t][e]
  unsigned short* kbuf = (unsigned short*)(ws + 37748736);   // 32 MB [bh][t][e]
  unsigned short* vbuf = (unsigned short*)(ws + 71303168);   // 32 MB [bh][e][t]
  unsigned short* abuf = (unsigned short*)(ws + 104857600);  // 32 MB [8192][2048]
  unsigned short* wqT  = (unsigned short*)(ws + 138412032);  //  1 MB [2048][256]
  unsigned short* wkT  = (unsigned short*)(ws + 139460608);
  unsigned short* wvT  = (unsigned short*)(ws + 140509184);
  unsigned short* wfcT = (unsigned short*)(ws + 141557760);  //  1 MB [256][2048]
  unsigned char*  mpk  = (unsigned char*)(ws + 142606336);   //  1 MB packed mask

  xcast_kernel<<<2048, 256, 0, stream>>>(x, xbf, 524288);
  mpack_kernel<<<4096, 256, 0, stream>>>(mask, mpk, 1048576);
  wtrans_kernel<<<dim3(32, 4), 256, 0, stream>>>(Wq, wqT, 256, 2048);
  wtrans_kernel<<<dim3(32, 4), 256, 0, stream>>>(Wk, wkT, 256, 2048);
  wtrans_kernel<<<dim3(32, 4), 256, 0, stream>>>(Wv, wvT, 256, 2048);
  wtrans_kernel<<<dim3(4, 32), 256, 0, stream>>>(Wfc, wfcT, 2048, 256);

  // Q gets the 1/TEMP = 1/16 scale baked in before bf16 store.
  gemm_kernel<1><<<dim3(16, 64), 256, 0, stream>>>(xbf, wqT, nullptr, qbuf,
                                                   8192, 2048, 256, 1.0f / 16.0f);
  gemm_kernel<1><<<dim3(16, 64), 256, 0, stream>>>(xbf, wkT, nullptr, kbuf,
                                                   8192, 2048, 256, 1.0f);
  gemm_kernel<2><<<dim3(16, 64), 256, 0, stream>>>(xbf, wvT, nullptr, vbuf,
                                                   8192, 2048, 256, 1.0f);

  attn_kernel<<<512, 512, 0, stream>>>(qbuf, kbuf, vbuf,
                                       (const unsigned long long*)mpk, abuf);

  gemm_kernel<0><<<dim3(2, 64), 256, 0, stream>>>(abuf, wfcT, bfc, out,
                                                  8192, 256, 2048, 1.0f);
}